// Round 1
// 440.031 us; speedup vs baseline: 1.0076x; 1.0076x over previous
//
#include <hip/hip_runtime.h>

#define DIM 1024
#define NQ 6

// One 256-thread block per row (grid-stride). Thread t owns out[d0..d0+3], d0=4t.
// Weights cached per-thread in registers: w1 frag 24f, w2 frag 24f, b2 4f.
//
// Reduction redesign vs previous version (which was DS-pipe-bound at ~35
// DS-ops/wave/row): fold stages now run on the VALU via DPP
//   xor1 -> quad_perm[1,0,3,2] (0xB1)
//   xor2 -> quad_perm[2,3,0,1] (0x4E)
//   xor7 -> row_half_mirror    (0x141)   (replaces xor4; needs remapped dirs)
//   xor8 -> row_ror:8          (0x128)   (vperm invariant under +8 mod 16)
// with fold-direction bits s1=(l^(l>>2))&1, s2=(l^(l>>1))&1, s3=(l>>2)&1,
// vperm = 4*s1+2*s2+s3 (lanes 0..7 hold {0,6,2,4,5,3,7,1} - bijective).
// Only xor16/xor32 remain as DS shuffles. Cross-wave combine reads collapse
// from 24x ds_read_b32 to 8x ds_read_b128. DS ops: 35 -> 11 per wave-row.
__device__ __forceinline__ float4 add4(float4 a, float4 b) {
    return make_float4(a.x + b.x, a.y + b.y, a.z + b.z, a.w + b.w);
}

template <int CTRL>
__device__ __forceinline__ float dpp_mov(float x) {
    return __int_as_float(__builtin_amdgcn_update_dpp(
        0, __float_as_int(x), CTRL, 0xF, 0xF, true));
}

__global__ __launch_bounds__(256, 4) void ffq_fused(
    const float* __restrict__ x,
    const float* __restrict__ w1,
    const float* __restrict__ b1,
    const float* __restrict__ theta,
    const float* __restrict__ w2,
    const float* __restrict__ b2,
    float* __restrict__ out,
    int n_rows)
{
    const int t    = threadIdx.x;
    const int lane = t & 63;
    const int wave = t >> 6;
    const int d0   = t * 4;

    // ---- register-cached weights (reused across all rows) ----
    float w1f[NQ][4];
#pragma unroll
    for (int q = 0; q < NQ; ++q) {
        float4 v = *reinterpret_cast<const float4*>(w1 + q * DIM + d0);
        w1f[q][0] = v.x; w1f[q][1] = v.y; w1f[q][2] = v.z; w1f[q][3] = v.w;
    }
    float w2f[4][NQ];  // w2f[i][q] = w2[(d0+i)*6 + q]; 24 contiguous floats, 16B aligned
    {
        const float4* wp = reinterpret_cast<const float4*>(w2 + (size_t)d0 * NQ);
        float* flat = &w2f[0][0];
#pragma unroll
        for (int i = 0; i < 6; ++i) {
            float4 v = wp[i];
            flat[4 * i + 0] = v.x; flat[4 * i + 1] = v.y;
            flat[4 * i + 2] = v.z; flat[4 * i + 3] = v.w;
        }
    }
    const float4 b2v = *reinterpret_cast<const float4*>(b2 + d0);
    float b1f[NQ], ctf[NQ];
#pragma unroll
    for (int q = 0; q < NQ; ++q) {
        b1f[q] = b1[q];
        ctf[q] = __cosf(theta[q]);
    }

    // fold-direction bits for the DPP butterfly (see header comment)
    const int s1 = (lane ^ (lane >> 2)) & 1;
    const int s2 = (lane ^ (lane >> 1)) & 1;
    const int s3 = (lane >> 2) & 1;
    const int vperm = 4 * s1 + 2 * s2 + s3;

    __shared__ __align__(16) float red[2][4][8];  // [parity][wave][value], 16B-aligned rows

    const int stride = gridDim.x;
    int r = blockIdx.x;
    int par = 0;

    float4 xv = make_float4(0.f, 0.f, 0.f, 0.f);
    if (r < n_rows) xv = *reinterpret_cast<const float4*>(x + (size_t)r * DIM + d0);

    while (r < n_rows) {
        // prefetch next row before the reduction/barrier
        const int rn = r + stride;
        float4 xn = make_float4(0.f, 0.f, 0.f, 0.f);
        if (rn < n_rows) xn = *reinterpret_cast<const float4*>(x + (size_t)rn * DIM + d0);

        // partial dot of this thread's 4 elements against each w1 row
        float p[8];
#pragma unroll
        for (int q = 0; q < NQ; ++q)
            p[q] = fmaf(xv.x, w1f[q][0],
                   fmaf(xv.y, w1f[q][1],
                   fmaf(xv.z, w1f[q][2], xv.w * w1f[q][3])));
        p[6] = 0.f; p[7] = 0.f;

        // ---- VALU butterfly: fold 8 values via DPP ----
        // stage 1: partner l^1 (quad_perm [1,0,3,2]); value bit2 = s1
        float r4[4];
#pragma unroll
        for (int i = 0; i < 4; ++i) {
            float send = s1 ? p[i] : p[i + 4];
            float keep = s1 ? p[i + 4] : p[i];
            r4[i] = keep + dpp_mov<0xB1>(send);
        }
        // stage 2: partner l^2 (quad_perm [2,3,0,1]); value bit1 = s2
        float r2[2];
#pragma unroll
        for (int i = 0; i < 2; ++i) {
            float send = s2 ? r4[i] : r4[i + 2];
            float keep = s2 ? r4[i + 2] : r4[i];
            r2[i] = keep + dpp_mov<0x4E>(send);
        }
        // stage 3: partner l^7 (row_half_mirror); value bit0 = s3
        float r1;
        {
            float send = s3 ? r2[0] : r2[1];
            float keep = s3 ? r2[1] : r2[0];
            r1 = keep + dpp_mov<0x141>(send);
        }
        // cross-group sums (same vperm on both sides of each exchange)
        r1 += dpp_mov<0x128>(r1);       // xor8 via row_ror:8 within 16
        r1 += __shfl_xor(r1, 16, 64);   // DS swizzle
        r1 += __shfl_xor(r1, 32, 64);   // DS permute

        if (lane < 8) red[par][wave][vperm] = r1;  // all 8 slots written (6,7 are 0)
        __syncthreads();

        // combine 4 wave partials with two b128 reads per wave, then cos
        const float4* rp = reinterpret_cast<const float4*>(&red[par][0][0]);
        float4 slo = add4(add4(rp[0], rp[2]), add4(rp[4], rp[6]));  // q0..q3
        float4 shi = add4(add4(rp[1], rp[3]), add4(rp[5], rp[7]));  // q4..q5 (zw unused)
        float qv[NQ];
        qv[0] = slo.x; qv[1] = slo.y; qv[2] = slo.z; qv[3] = slo.w;
        qv[4] = shi.x; qv[5] = shi.y;
#pragma unroll
        for (int q = 0; q < NQ; ++q)
            qv[q] = __cosf(qv[q] + b1f[q]) * ctf[q];

        float4 o = b2v;
#pragma unroll
        for (int q = 0; q < NQ; ++q) {
            o.x = fmaf(qv[q], w2f[0][q], o.x);
            o.y = fmaf(qv[q], w2f[1][q], o.y);
            o.z = fmaf(qv[q], w2f[2][q], o.z);
            o.w = fmaf(qv[q], w2f[3][q], o.w);
        }
        o.x = fmaxf(o.x, 0.f); o.y = fmaxf(o.y, 0.f);
        o.z = fmaxf(o.z, 0.f); o.w = fmaxf(o.w, 0.f);
        *reinterpret_cast<float4*>(out + (size_t)r * DIM + d0) = o;

        xv = xn;
        r = rn;
        par ^= 1;
    }
}

extern "C" void kernel_launch(void* const* d_in, const int* in_sizes, int n_in,
                              void* d_out, int out_size, void* d_ws, size_t ws_size,
                              hipStream_t stream) {
    const float* x     = (const float*)d_in[0];
    const float* w1    = (const float*)d_in[1];
    const float* b1    = (const float*)d_in[2];
    const float* theta = (const float*)d_in[3];
    const float* w2    = (const float*)d_in[4];
    const float* b2    = (const float*)d_in[5];
    float* out = (float*)d_out;

    const int n_rows = in_sizes[0] / DIM;  // B*S = 65536
    const int blocks = 1024;               // 4 blocks/CU resident at <=128 VGPR
    ffq_fused<<<blocks, 256, 0, stream>>>(x, w1, b1, theta, w2, b2, out, n_rows);
}